// Round 8
// baseline (884.723 us; speedup 1.0000x reference)
//
#include <hip/hip_runtime.h>
#include <cstdint>
#include <cstddef>

#define NFEAT 500
#define NHID  128
#define NCLASS 40

typedef __attribute__((ext_vector_type(8))) short bf16x8;
typedef __attribute__((ext_vector_type(4))) float f32x4;

__device__ __forceinline__ unsigned short f2bf(float f) {
    union { float f; unsigned u; } v; v.f = f;
    unsigned u = v.u;
    unsigned r = u + 0x7FFF + ((u >> 16) & 1);   // round-to-nearest-even
    return (unsigned short)(r >> 16);
}
__device__ __forceinline__ float bf2f(unsigned short h) {
    union { unsigned u; float f; } v; v.u = ((unsigned)h) << 16; return v.f;
}

// ---------------- CSR construction ----------------

__global__ void k_hist(const int* __restrict__ row, int E, int* __restrict__ counts) {
    int i = blockIdx.x * 256 + threadIdx.x;
    if (i < E) atomicAdd(&counts[row[i]], 1);
}

__global__ void k_block_sum(const int* __restrict__ counts, int n, int* __restrict__ partials) {
    __shared__ int tmp[256];
    int i = blockIdx.x * 256 + threadIdx.x;
    tmp[threadIdx.x] = (i < n) ? counts[i] : 0;
    __syncthreads();
    for (int o = 128; o > 0; o >>= 1) {
        if (threadIdx.x < o) tmp[threadIdx.x] += tmp[threadIdx.x + o];
        __syncthreads();
    }
    if (threadIdx.x == 0) partials[blockIdx.x] = tmp[0];
}

__global__ void k_scan_partials(int* __restrict__ partials, int nb) {
    __shared__ int tmp[512];
    int t = threadIdx.x;
    int v = (t < nb) ? partials[t] : 0;
    tmp[t] = v;
    __syncthreads();
    for (int o = 1; o < 512; o <<= 1) {
        int add = (t >= o) ? tmp[t - o] : 0;
        __syncthreads();
        tmp[t] += add;
        __syncthreads();
    }
    if (t < nb) partials[t] = tmp[t] - v;   // exclusive
}

// also zeroes counts for reuse as cursor
__global__ void k_scan_counts(int* __restrict__ counts, const int* __restrict__ partials,
                              int* __restrict__ row_ptr, int n) {
    __shared__ int tmp[256];
    int t = threadIdx.x;
    int i = blockIdx.x * 256 + t;
    int v = (i < n) ? counts[i] : 0;
    tmp[t] = v;
    __syncthreads();
    for (int o = 1; o < 256; o <<= 1) {
        int add = (t >= o) ? tmp[t - o] : 0;
        __syncthreads();
        tmp[t] += add;
        __syncthreads();
    }
    int incl = tmp[t];
    int base = partials[blockIdx.x];
    if (i < n) {
        row_ptr[i] = base + incl - v;
        counts[i] = 0;
    }
    if (i == n - 1) row_ptr[n] = base + incl;
}

__global__ void k_scatter(const int* __restrict__ row, const int* __restrict__ col,
                          const float* __restrict__ w, int E,
                          const int* __restrict__ row_ptr, int* __restrict__ cursor,
                          uint2* __restrict__ csr_cw) {
    int i = blockIdx.x * 256 + threadIdx.x;
    if (i < E) {
        int r = row[i];
        int p = row_ptr[r] + atomicAdd(&cursor[r], 1);
        csr_cw[p] = make_uint2((unsigned)col[i], __float_as_uint(w[i]));
    }
}

// ---------------- fused weight prep: all four W -> Wt (transposed, zero-padded) + zero counts ----------------

__device__ __forceinline__ void prep1(const float* __restrict__ W, unsigned short* __restrict__ Wt,
                                      int K, int Norig, int Kpad, int idx) {
    int n = idx / Kpad, k = idx % Kpad;
    unsigned short v = 0;
    if (k < K && n < Norig) v = f2bf(W[(size_t)k * Norig + n]);
    Wt[idx] = v;
}

__global__ void k_prep_all(const float* __restrict__ W1, const float* __restrict__ W2,
                           const float* __restrict__ W3, const float* __restrict__ W4,
                           unsigned short* __restrict__ Wt1, unsigned short* __restrict__ Wt2,
                           unsigned short* __restrict__ Wt3, unsigned short* __restrict__ Wt4,
                           int* __restrict__ counts, int n) {
    int idx = blockIdx.x * 256 + threadIdx.x;
    if (idx < n) counts[idx] = 0;
    if (idx < 65536) {                                  // 128 x 512
        prep1(W1, Wt1, NFEAT, NHID, 512, idx);
    } else if (idx < 65536 + 16384) {                   // 128 x 128
        prep1(W2, Wt2, NHID, NHID, 128, idx - 65536);
    } else if (idx < 65536 + 32768) {
        prep1(W3, Wt3, NHID, NHID, 128, idx - 65536 - 16384);
    } else if (idx < 65536 + 32768 + 6144) {            // 48 x 128
        prep1(W4, Wt4, NHID, NCLASS, 128, idx - 65536 - 32768);
    }
}

// ---------------- MFMA GEMM (round-0 template, best measured: l1 = 117 us) ----------------
// BM=128, BK=32, 256 threads (4 waves). A: LDS double-buffered with register prefetch,
// ONE barrier per K-iter. B: direct global->fragment loads (Wt is [n][k], exactly MFMA
// B-layout; 128 KB -> L2-resident). Buffers padded to Mpad rows; only fp32-A guards M.
// NOTE (rounds 1-6): every "improvement" on this structure (swizzle+deep pipe, no-LDS
// direct, VGPR rotate-3, per-wave gl_lds ring, B-lead vmcnt) measured 137-223 us vs
// this template's 117. The pattern's ~1.2-1.7 TB/s is a latency*outstanding equilibrium
// set by the HW VMEM queue, not by source-level scheduling. Do not re-litigate.

template<bool AFP32, int BN, int CN, int CPITCH>
__global__ __launch_bounds__(256) void k_gemm_mfma(const void* __restrict__ Ain,
                                                   const unsigned short* __restrict__ Wt,
                                                   unsigned short* __restrict__ C,
                                                   int M, int K, int Kpad) {
    constexpr int P  = 40;                     // LDS pitch (ushorts) = 80 B
    constexpr int NW = (BN == 128) ? 2 : 1;
    constexpr int MW = 4 / NW;
    constexpr int TM = 128 / (MW * 16);
    constexpr int TN = BN / (NW * 16);
    __shared__ unsigned short As[2][128][P];   // 20.0 KB total

    const int t = threadIdx.x;
    const int lane = t & 63;
    const int w = t >> 6;
    const int wm = w / NW, wn = w % NW;
    const int mbase = blockIdx.x * 128;
    const int l15 = lane & 15, quad = lane >> 4;

    const float* Af = (const float*)Ain;
    const unsigned short* Ab = (const unsigned short*)Ain;

    f32x4 acc[TM][TN];
#pragma unroll
    for (int mi = 0; mi < TM; mi++)
#pragma unroll
        for (int ni = 0; ni < TN; ni++)
            acc[mi][ni] = (f32x4){0.f, 0.f, 0.f, 0.f};

    // A staging registers (prefetch)
    float4 ra_f[4];   // fp32 path: 16 floats/thread
    uint4  ra_b[2];   // bf16 path: 2x16B/thread

    auto loadA = [&](int k0) {
        if (AFP32) {
#pragma unroll
            for (int p = 0; p < 4; p++) {
                int idx = p * 256 + t;
                int m = idx >> 3, ch = idx & 7;
                int gm = mbase + m, gk = k0 + ch * 4;
                float4 v = make_float4(0.f, 0.f, 0.f, 0.f);
                if (gm < M && gk + 4 <= K) v = *(const float4*)(Af + (size_t)gm * K + gk);
                ra_f[p] = v;
            }
        } else {
#pragma unroll
            for (int p = 0; p < 2; p++) {
                int idx = p * 256 + t;
                int m = idx >> 2, ch = idx & 3;
                ra_b[p] = *(const uint4*)(Ab + (size_t)(mbase + m) * Kpad + k0 + ch * 8);
            }
        }
    };
    auto storeLDS = [&](int buf) {
        if (AFP32) {
#pragma unroll
            for (int p = 0; p < 4; p++) {
                int idx = p * 256 + t;
                int m = idx >> 3, ch = idx & 7;
                float4 v = ra_f[p];
                unsigned long long pk = (unsigned long long)f2bf(v.x)
                                      | ((unsigned long long)f2bf(v.y) << 16)
                                      | ((unsigned long long)f2bf(v.z) << 32)
                                      | ((unsigned long long)f2bf(v.w) << 48);
                *(unsigned long long*)&As[buf][m][ch * 4] = pk;
            }
        } else {
#pragma unroll
            for (int p = 0; p < 2; p++) {
                int idx = p * 256 + t;
                int m = idx >> 2, ch = idx & 3;
                *(uint4*)&As[buf][m][ch * 8] = ra_b[p];
            }
        }
    };

    const int nIter = Kpad >> 5;
    loadA(0);
    storeLDS(0);
    __syncthreads();

    for (int it = 0; it < nIter; it++) {
        const int cur = it & 1;
        const int k0 = it << 5;
        const bool more = (it + 1) < nIter;
        if (more) loadA(k0 + 32);              // global loads in flight over compute

        // B fragments: direct global (L2-hot)
        bf16x8 bfr[TN];
#pragma unroll
        for (int ni = 0; ni < TN; ni++)
            bfr[ni] = *(const bf16x8*)(Wt + (size_t)(wn * (TN * 16) + ni * 16 + l15) * Kpad + k0 + quad * 8);

        bf16x8 afr[TM];
#pragma unroll
        for (int mi = 0; mi < TM; mi++)
            afr[mi] = *(const bf16x8*)&As[cur][wm * (TM * 16) + mi * 16 + l15][quad * 8];

#pragma unroll
        for (int mi = 0; mi < TM; mi++)
#pragma unroll
            for (int ni = 0; ni < TN; ni++)
                acc[mi][ni] = __builtin_amdgcn_mfma_f32_16x16x32_bf16(afr[mi], bfr[ni], acc[mi][ni], 0, 0, 0);

        if (more) {
            storeLDS(cur ^ 1);                 // waits on prefetch, writes other buffer
            __syncthreads();                   // ONE barrier per iter
        }
    }

    // epilogue: C/D layout col=lane&15, row=quad*4+reg ; rows padded, no M guard
#pragma unroll
    for (int mi = 0; mi < TM; mi++) {
#pragma unroll
        for (int r = 0; r < 4; r++) {
            int gm = mbase + wm * (TM * 16) + mi * 16 + quad * 4 + r;
#pragma unroll
            for (int ni = 0; ni < TN; ni++) {
                int gn = wn * (TN * 16) + ni * 16 + l15;
                if (gn < CN) C[(size_t)gm * CPITCH + gn] = f2bf(acc[mi][ni][r]);
            }
        }
    }
}

// ---------------- SpMM (width 128, bf16) + bias + optional ReLU ----------------
// Round-8: HALF-WAVE decomposition. 32 lanes cover one 256B S-row via uint2
// (8B/lane); the two halves process different edges concurrently -> with unroll-8,
// 16 edges (4KB) in flight per wave (2x round-7's MLP). Predicated tail (clamped
// index, zero weight) keeps the hot loop to 1-2 iterations at avg degree 16.
// Epilogue: one shfl_xor(32) cross-half reduce; lower half adds bias/ReLU, stores
// uint2. Reduction order per feature: in-order within each half, halves summed
// once at the end (same split-accumulator pattern as round 7).

__global__ __launch_bounds__(256) void k_spmm128(const unsigned short* __restrict__ S,
                                                 const int* __restrict__ rp,
                                                 const uint2* __restrict__ cw,
                                                 const float* __restrict__ bias,
                                                 unsigned short* __restrict__ out,
                                                 int n, int do_relu) {
    int wid  = threadIdx.x >> 6;
    int lane = threadIdx.x & 63;
    int sl   = lane & 31;                 // sub-lane within half
    int h    = lane >> 5;                 // half id (0/1)
    int node = blockIdx.x * 4 + wid;
    if (node >= n) return;
    int s = rp[node], e = rp[node + 1];
    const unsigned* Su = (const unsigned*)S;

    float c0 = 0.f, c1 = 0.f, c2 = 0.f, c3 = 0.f;
    for (int i = s; i < e; i += 16) {
        int base = i + 8 * h;
#pragma unroll
        for (int j = 0; j < 8; j++) {
            int idx = base + j;
            bool ok = idx < e;
            uint2 ed = cw[ok ? idx : s];
            float wgt = ok ? __uint_as_float(ed.y) : 0.f;
            uint2 v = *(const uint2*)(Su + (size_t)ed.x * 64 + 2 * sl);
            c0 = fmaf(wgt, bf2f((unsigned short)v.x), c0);
            c1 = fmaf(wgt, bf2f((unsigned short)(v.x >> 16)), c1);
            c2 = fmaf(wgt, bf2f((unsigned short)v.y), c2);
            c3 = fmaf(wgt, bf2f((unsigned short)(v.y >> 16)), c3);
        }
    }
    // cross-half reduce: feature f=4*sl+k lives in lane sl and lane 32+sl
    c0 += __shfl_xor(c0, 32, 64);
    c1 += __shfl_xor(c1, 32, 64);
    c2 += __shfl_xor(c2, 32, 64);
    c3 += __shfl_xor(c3, 32, 64);
    if (h == 0) {
        c0 += bias[sl * 4 + 0];
        c1 += bias[sl * 4 + 1];
        c2 += bias[sl * 4 + 2];
        c3 += bias[sl * 4 + 3];
        if (do_relu) {
            c0 = fmaxf(c0, 0.f); c1 = fmaxf(c1, 0.f);
            c2 = fmaxf(c2, 0.f); c3 = fmaxf(c3, 0.f);
        }
        uint2 o;
        o.x = (unsigned)f2bf(c0) | ((unsigned)f2bf(c1) << 16);
        o.y = (unsigned)f2bf(c2) | ((unsigned)f2bf(c3) << 16);
        *(uint2*)((unsigned*)(out + (size_t)node * NHID) + 2 * sl) = o;
    }
}

// ---------------- SpMM (width 40, bf16 pitch 40) + bias + log_softmax -> fp32 out ----------------
// unroll-8 MLP (round-7 version, kept).

__global__ __launch_bounds__(256) void k_spmm40_lsm(const unsigned short* __restrict__ S,
                                                    const int* __restrict__ rp,
                                                    const uint2* __restrict__ cw,
                                                    const float* __restrict__ bias,
                                                    float* __restrict__ out,
                                                    int n) {
    int wid  = threadIdx.x >> 6;
    int lane = threadIdx.x & 63;
    int node = blockIdx.x * 4 + wid;
    if (node >= n) return;
    int s = rp[node], e = rp[node + 1];
    float a0 = 0.f, a1 = 0.f, a2 = 0.f, a3 = 0.f;
    int i = s;
    bool act = lane < NCLASS;
    for (; i + 8 <= e; i += 8) {
        uint2 e0 = cw[i],     e1 = cw[i + 1], e2 = cw[i + 2], e3 = cw[i + 3];
        uint2 e4 = cw[i + 4], e5 = cw[i + 5], e6 = cw[i + 6], e7 = cw[i + 7];
        if (act) {
            float v0 = bf2f(S[(size_t)e0.x * NCLASS + lane]);
            float v1 = bf2f(S[(size_t)e1.x * NCLASS + lane]);
            float v2 = bf2f(S[(size_t)e2.x * NCLASS + lane]);
            float v3 = bf2f(S[(size_t)e3.x * NCLASS + lane]);
            float v4 = bf2f(S[(size_t)e4.x * NCLASS + lane]);
            float v5 = bf2f(S[(size_t)e5.x * NCLASS + lane]);
            float v6 = bf2f(S[(size_t)e6.x * NCLASS + lane]);
            float v7 = bf2f(S[(size_t)e7.x * NCLASS + lane]);
            a0 = fmaf(__uint_as_float(e0.y), v0, a0);
            a1 = fmaf(__uint_as_float(e1.y), v1, a1);
            a2 = fmaf(__uint_as_float(e2.y), v2, a2);
            a3 = fmaf(__uint_as_float(e3.y), v3, a3);
            a0 = fmaf(__uint_as_float(e4.y), v4, a0);
            a1 = fmaf(__uint_as_float(e5.y), v5, a1);
            a2 = fmaf(__uint_as_float(e6.y), v6, a2);
            a3 = fmaf(__uint_as_float(e7.y), v7, a3);
        }
    }
    for (; i + 4 <= e; i += 4) {
        uint2 e0 = cw[i], e1 = cw[i + 1], e2 = cw[i + 2], e3 = cw[i + 3];
        if (act) {
            float v0 = bf2f(S[(size_t)e0.x * NCLASS + lane]);
            float v1 = bf2f(S[(size_t)e1.x * NCLASS + lane]);
            float v2 = bf2f(S[(size_t)e2.x * NCLASS + lane]);
            float v3 = bf2f(S[(size_t)e3.x * NCLASS + lane]);
            a0 = fmaf(__uint_as_float(e0.y), v0, a0);
            a1 = fmaf(__uint_as_float(e1.y), v1, a1);
            a2 = fmaf(__uint_as_float(e2.y), v2, a2);
            a3 = fmaf(__uint_as_float(e3.y), v3, a3);
        }
    }
    for (; i < e; i++) {
        uint2 e0 = cw[i];
        if (act) a0 = fmaf(__uint_as_float(e0.y), bf2f(S[(size_t)e0.x * NCLASS + lane]), a0);
    }
    float acc = (a0 + a1) + (a2 + a3);
    float logit = act ? acc + bias[lane] : -INFINITY;
    float m = logit;
#pragma unroll
    for (int o = 32; o >= 1; o >>= 1) m = fmaxf(m, __shfl_xor(m, o, 64));
    float ex = act ? expf(logit - m) : 0.f;
    float ssum = ex;
#pragma unroll
    for (int o = 32; o >= 1; o >>= 1) ssum += __shfl_xor(ssum, o, 64);
    if (act) {
        float r = logit - m - logf(ssum);
        __builtin_nontemporal_store(r, out + (size_t)node * NCLASS + lane);
    }
}

// ---------------- launch ----------------

extern "C" void kernel_launch(void* const* d_in, const int* in_sizes, int n_in,
                              void* d_out, int out_size, void* d_ws, size_t ws_size,
                              hipStream_t stream) {
    const float* x  = (const float*)d_in[0];
    const int* row  = (const int*)d_in[1];
    const int* col  = (const int*)d_in[2];
    const float* ew = (const float*)d_in[3];
    const float* W1 = (const float*)d_in[4];
    const float* b1 = (const float*)d_in[5];
    const float* W2 = (const float*)d_in[6];
    const float* b2 = (const float*)d_in[7];
    const float* W3 = (const float*)d_in[8];
    const float* b3 = (const float*)d_in[9];
    const float* W4 = (const float*)d_in[10];
    const float* b4 = (const float*)d_in[11];
    float* out = (float*)d_out;

    const int Nn = in_sizes[0] / NFEAT;
    const int E  = in_sizes[1];
    const int NB = (Nn + 255) / 256;
    const int Mpad = (Nn + 127) & ~127;

    char* ws = (char*)d_ws;
    size_t off = 0;
    auto alloc = [&](size_t bytes) {
        size_t o = off;
        off = (off + bytes + 255) & ~(size_t)255;
        return o;
    };
    int*   row_ptr  = (int*)(ws + alloc((size_t)(Nn + 1) * 4));
    int*   counts   = (int*)(ws + alloc((size_t)Nn * 4));       // also reused as cursor
    int*   partials = (int*)(ws + alloc((size_t)NB * 4));
    uint2* csr_cw   = (uint2*)(ws + alloc((size_t)E * 8));
    unsigned short* Sb  = (unsigned short*)(ws + alloc((size_t)Mpad * NHID * 2));
    unsigned short* Hb  = (unsigned short*)(ws + alloc((size_t)Mpad * NHID * 2));
    unsigned short* S4b = (unsigned short*)(ws + alloc((size_t)Mpad * NCLASS * 2));
    unsigned short* Wt1 = (unsigned short*)(ws + alloc((size_t)128 * 512 * 2));
    unsigned short* Wt2 = (unsigned short*)(ws + alloc((size_t)128 * 128 * 2));
    unsigned short* Wt3 = (unsigned short*)(ws + alloc((size_t)128 * 128 * 2));
    unsigned short* Wt4 = (unsigned short*)(ws + alloc((size_t)48 * 128 * 2));

    // ---- fused weight prep + counts zeroing (1 launch, was 5) ----
    {
        int total = 65536 + 32768 + 6144;
        if (Nn > total) total = Nn;
        k_prep_all<<<(total + 255) / 256, 256, 0, stream>>>(W1, W2, W3, W4,
                                                            Wt1, Wt2, Wt3, Wt4,
                                                            counts, Nn);
    }

    // ---- CSR build ----
    k_hist<<<(E + 255) / 256, 256, 0, stream>>>(row, E, counts);
    k_block_sum<<<NB, 256, 0, stream>>>(counts, Nn, partials);
    k_scan_partials<<<1, 512, 0, stream>>>(partials, NB);
    k_scan_counts<<<NB, 256, 0, stream>>>(counts, partials, row_ptr, Nn);
    k_scatter<<<(E + 255) / 256, 256, 0, stream>>>(row, col, ew, E, row_ptr, counts, csr_cw);

    const int gblocks = Mpad / 128;
    const int spmm_blocks = (Nn + 3) / 4;

    // layer 1: x @ W1 -> Sb ; spmm+b1+relu -> Hb
    k_gemm_mfma<true, 128, 128, 128><<<gblocks, 256, 0, stream>>>(x, Wt1, Sb, Nn, NFEAT, 512);
    k_spmm128<<<spmm_blocks, 256, 0, stream>>>(Sb, row_ptr, csr_cw, b1, Hb, Nn, 1);
    // layer 2
    k_gemm_mfma<false, 128, 128, 128><<<gblocks, 256, 0, stream>>>(Hb, Wt2, Sb, Nn, NHID, NHID);
    k_spmm128<<<spmm_blocks, 256, 0, stream>>>(Sb, row_ptr, csr_cw, b2, Hb, Nn, 1);
    // layer 3
    k_gemm_mfma<false, 128, 128, 128><<<gblocks, 256, 0, stream>>>(Hb, Wt3, Sb, Nn, NHID, NHID);
    k_spmm128<<<spmm_blocks, 256, 0, stream>>>(Sb, row_ptr, csr_cw, b3, Hb, Nn, 1);
    // layer 4: Hb @ W4 -> S4b[N,40] ; spmm+b4+log_softmax -> out (fp32)
    k_gemm_mfma<false, 48, 40, 40><<<gblocks, 256, 0, stream>>>(Hb, Wt4, S4b, Nn, NHID, NHID);
    k_spmm40_lsm<<<spmm_blocks, 256, 0, stream>>>(S4b, row_ptr, csr_cw, b4, out, Nn);
}

// Round 9
// 823.764 us; speedup vs baseline: 1.0740x; 1.0740x over previous
//
#include <hip/hip_runtime.h>
#include <cstdint>
#include <cstddef>

#define NFEAT 500
#define NHID  128
#define NCLASS 40

typedef __attribute__((ext_vector_type(8))) short bf16x8;
typedef __attribute__((ext_vector_type(4))) float f32x4;

__device__ __forceinline__ unsigned short f2bf(float f) {
    union { float f; unsigned u; } v; v.f = f;
    unsigned u = v.u;
    unsigned r = u + 0x7FFF + ((u >> 16) & 1);   // round-to-nearest-even
    return (unsigned short)(r >> 16);
}
__device__ __forceinline__ float bf2f(unsigned short h) {
    union { unsigned u; float f; } v; v.u = ((unsigned)h) << 16; return v.f;
}

// ---------------- CSR construction ----------------

__global__ void k_hist(const int* __restrict__ row, int E, int* __restrict__ counts) {
    int i = blockIdx.x * 256 + threadIdx.x;
    if (i < E) atomicAdd(&counts[row[i]], 1);
}

__global__ void k_block_sum(const int* __restrict__ counts, int n, int* __restrict__ partials) {
    __shared__ int tmp[256];
    int i = blockIdx.x * 256 + threadIdx.x;
    tmp[threadIdx.x] = (i < n) ? counts[i] : 0;
    __syncthreads();
    for (int o = 128; o > 0; o >>= 1) {
        if (threadIdx.x < o) tmp[threadIdx.x] += tmp[threadIdx.x + o];
        __syncthreads();
    }
    if (threadIdx.x == 0) partials[blockIdx.x] = tmp[0];
}

__global__ void k_scan_partials(int* __restrict__ partials, int nb) {
    __shared__ int tmp[512];
    int t = threadIdx.x;
    int v = (t < nb) ? partials[t] : 0;
    tmp[t] = v;
    __syncthreads();
    for (int o = 1; o < 512; o <<= 1) {
        int add = (t >= o) ? tmp[t - o] : 0;
        __syncthreads();
        tmp[t] += add;
        __syncthreads();
    }
    if (t < nb) partials[t] = tmp[t] - v;   // exclusive
}

// also zeroes counts for reuse as cursor
__global__ void k_scan_counts(int* __restrict__ counts, const int* __restrict__ partials,
                              int* __restrict__ row_ptr, int n) {
    __shared__ int tmp[256];
    int t = threadIdx.x;
    int i = blockIdx.x * 256 + t;
    int v = (i < n) ? counts[i] : 0;
    tmp[t] = v;
    __syncthreads();
    for (int o = 1; o < 256; o <<= 1) {
        int add = (t >= o) ? tmp[t - o] : 0;
        __syncthreads();
        tmp[t] += add;
        __syncthreads();
    }
    int incl = tmp[t];
    int base = partials[blockIdx.x];
    if (i < n) {
        row_ptr[i] = base + incl - v;
        counts[i] = 0;
    }
    if (i == n - 1) row_ptr[n] = base + incl;
}

__global__ void k_scatter(const int* __restrict__ row, const int* __restrict__ col,
                          const float* __restrict__ w, int E,
                          const int* __restrict__ row_ptr, int* __restrict__ cursor,
                          uint2* __restrict__ csr_cw) {
    int i = blockIdx.x * 256 + threadIdx.x;
    if (i < E) {
        int r = row[i];
        int p = row_ptr[r] + atomicAdd(&cursor[r], 1);
        csr_cw[p] = make_uint2((unsigned)col[i], __float_as_uint(w[i]));
    }
}

// ---------------- fused weight prep: all four W -> Wt (transposed, zero-padded) + zero counts ----------------

__device__ __forceinline__ void prep1(const float* __restrict__ W, unsigned short* __restrict__ Wt,
                                      int K, int Norig, int Kpad, int idx) {
    int n = idx / Kpad, k = idx % Kpad;
    unsigned short v = 0;
    if (k < K && n < Norig) v = f2bf(W[(size_t)k * Norig + n]);
    Wt[idx] = v;
}

__global__ void k_prep_all(const float* __restrict__ W1, const float* __restrict__ W2,
                           const float* __restrict__ W3, const float* __restrict__ W4,
                           unsigned short* __restrict__ Wt1, unsigned short* __restrict__ Wt2,
                           unsigned short* __restrict__ Wt3, unsigned short* __restrict__ Wt4,
                           int* __restrict__ counts, int n) {
    int idx = blockIdx.x * 256 + threadIdx.x;
    if (idx < n) counts[idx] = 0;
    if (idx < 65536) {                                  // 128 x 512
        prep1(W1, Wt1, NFEAT, NHID, 512, idx);
    } else if (idx < 65536 + 16384) {                   // 128 x 128
        prep1(W2, Wt2, NHID, NHID, 128, idx - 65536);
    } else if (idx < 65536 + 32768) {
        prep1(W3, Wt3, NHID, NHID, 128, idx - 65536 - 16384);
    } else if (idx < 65536 + 32768 + 6144) {            // 48 x 128
        prep1(W4, Wt4, NHID, NCLASS, 128, idx - 65536 - 32768);
    }
}

// ---------------- MFMA GEMM (round-0 template, best measured: l1 = 117 us) ----------------
// BM=128, BK=32, 256 threads (4 waves). A: LDS double-buffered with register prefetch,
// ONE barrier per K-iter. B: direct global->fragment loads (Wt is [n][k], exactly MFMA
// B-layout; 128 KB -> L2-resident). Buffers padded to Mpad rows; only fp32-A guards M.
// NOTE (rounds 1-6): every "improvement" on this structure (swizzle+deep pipe, no-LDS
// direct, VGPR rotate-3, per-wave gl_lds ring, B-lead vmcnt) measured 137-223 us vs
// this template's 117. The pattern's ~1.2-1.7 TB/s is a latency*outstanding equilibrium
// set by the HW VMEM queue, not by source-level scheduling. Do not re-litigate.

template<bool AFP32, int BN, int CN, int CPITCH>
__global__ __launch_bounds__(256) void k_gemm_mfma(const void* __restrict__ Ain,
                                                   const unsigned short* __restrict__ Wt,
                                                   unsigned short* __restrict__ C,
                                                   int M, int K, int Kpad) {
    constexpr int P  = 40;                     // LDS pitch (ushorts) = 80 B
    constexpr int NW = (BN == 128) ? 2 : 1;
    constexpr int MW = 4 / NW;
    constexpr int TM = 128 / (MW * 16);
    constexpr int TN = BN / (NW * 16);
    __shared__ unsigned short As[2][128][P];   // 20.0 KB total

    const int t = threadIdx.x;
    const int lane = t & 63;
    const int w = t >> 6;
    const int wm = w / NW, wn = w % NW;
    const int mbase = blockIdx.x * 128;
    const int l15 = lane & 15, quad = lane >> 4;

    const float* Af = (const float*)Ain;
    const unsigned short* Ab = (const unsigned short*)Ain;

    f32x4 acc[TM][TN];
#pragma unroll
    for (int mi = 0; mi < TM; mi++)
#pragma unroll
        for (int ni = 0; ni < TN; ni++)
            acc[mi][ni] = (f32x4){0.f, 0.f, 0.f, 0.f};

    // A staging registers (prefetch)
    float4 ra_f[4];   // fp32 path: 16 floats/thread
    uint4  ra_b[2];   // bf16 path: 2x16B/thread

    auto loadA = [&](int k0) {
        if (AFP32) {
#pragma unroll
            for (int p = 0; p < 4; p++) {
                int idx = p * 256 + t;
                int m = idx >> 3, ch = idx & 7;
                int gm = mbase + m, gk = k0 + ch * 4;
                float4 v = make_float4(0.f, 0.f, 0.f, 0.f);
                if (gm < M && gk + 4 <= K) v = *(const float4*)(Af + (size_t)gm * K + gk);
                ra_f[p] = v;
            }
        } else {
#pragma unroll
            for (int p = 0; p < 2; p++) {
                int idx = p * 256 + t;
                int m = idx >> 2, ch = idx & 3;
                ra_b[p] = *(const uint4*)(Ab + (size_t)(mbase + m) * Kpad + k0 + ch * 8);
            }
        }
    };
    auto storeLDS = [&](int buf) {
        if (AFP32) {
#pragma unroll
            for (int p = 0; p < 4; p++) {
                int idx = p * 256 + t;
                int m = idx >> 3, ch = idx & 7;
                float4 v = ra_f[p];
                unsigned long long pk = (unsigned long long)f2bf(v.x)
                                      | ((unsigned long long)f2bf(v.y) << 16)
                                      | ((unsigned long long)f2bf(v.z) << 32)
                                      | ((unsigned long long)f2bf(v.w) << 48);
                *(unsigned long long*)&As[buf][m][ch * 4] = pk;
            }
        } else {
#pragma unroll
            for (int p = 0; p < 2; p++) {
                int idx = p * 256 + t;
                int m = idx >> 2, ch = idx & 3;
                *(uint4*)&As[buf][m][ch * 8] = ra_b[p];
            }
        }
    };

    const int nIter = Kpad >> 5;
    loadA(0);
    storeLDS(0);
    __syncthreads();

    for (int it = 0; it < nIter; it++) {
        const int cur = it & 1;
        const int k0 = it << 5;
        const bool more = (it + 1) < nIter;
        if (more) loadA(k0 + 32);              // global loads in flight over compute

        // B fragments: direct global (L2-hot)
        bf16x8 bfr[TN];
#pragma unroll
        for (int ni = 0; ni < TN; ni++)
            bfr[ni] = *(const bf16x8*)(Wt + (size_t)(wn * (TN * 16) + ni * 16 + l15) * Kpad + k0 + quad * 8);

        bf16x8 afr[TM];
#pragma unroll
        for (int mi = 0; mi < TM; mi++)
            afr[mi] = *(const bf16x8*)&As[cur][wm * (TM * 16) + mi * 16 + l15][quad * 8];

#pragma unroll
        for (int mi = 0; mi < TM; mi++)
#pragma unroll
            for (int ni = 0; ni < TN; ni++)
                acc[mi][ni] = __builtin_amdgcn_mfma_f32_16x16x32_bf16(afr[mi], bfr[ni], acc[mi][ni], 0, 0, 0);

        if (more) {
            storeLDS(cur ^ 1);                 // waits on prefetch, writes other buffer
            __syncthreads();                   // ONE barrier per iter
        }
    }

    // epilogue: C/D layout col=lane&15, row=quad*4+reg ; rows padded, no M guard
#pragma unroll
    for (int mi = 0; mi < TM; mi++) {
#pragma unroll
        for (int r = 0; r < 4; r++) {
            int gm = mbase + wm * (TM * 16) + mi * 16 + quad * 4 + r;
#pragma unroll
            for (int ni = 0; ni < TN; ni++) {
                int gn = wn * (TN * 16) + ni * 16 + l15;
                if (gn < CN) C[(size_t)gm * CPITCH + gn] = f2bf(acc[mi][ni][r]);
            }
        }
    }
}

// ---------------- SpMM (width 128, bf16) + bias + optional ReLU ----------------
// Round-9: full-wave (round-7 structure, EXACT work - round-8's predicated half-wave
// wasted ~50% gathers on degree<16 nodes and regressed +59us) with a 16-deep leading
// stage: 16 edges = 4KB of gathers in flight per wave (2x round 7), tails 8/4/1.
// All arrays constant-indexed after unroll (SROA-safe).

__global__ __launch_bounds__(256) void k_spmm128(const unsigned short* __restrict__ S,
                                                 const int* __restrict__ rp,
                                                 const uint2* __restrict__ cw,
                                                 const float* __restrict__ bias,
                                                 unsigned short* __restrict__ out,
                                                 int n, int do_relu) {
    int wid  = threadIdx.x >> 6;
    int lane = threadIdx.x & 63;
    int node = blockIdx.x * 4 + wid;
    if (node >= n) return;
    int s = rp[node], e = rp[node + 1];
    const unsigned* Su = (const unsigned*)S;

    float ax[4] = {0.f, 0.f, 0.f, 0.f};
    float ay[4] = {0.f, 0.f, 0.f, 0.f};
    int i = s;
    for (; i + 16 <= e; i += 16) {
        uint2 ed[16];
#pragma unroll
        for (int j = 0; j < 16; j++) ed[j] = cw[i + j];
        unsigned v[16];
#pragma unroll
        for (int j = 0; j < 16; j++) v[j] = Su[(size_t)ed[j].x * 64 + lane];
#pragma unroll
        for (int j = 0; j < 16; j++) {
            float wj = __uint_as_float(ed[j].y);
            ax[j & 3] = fmaf(wj, bf2f((unsigned short)v[j]), ax[j & 3]);
            ay[j & 3] = fmaf(wj, bf2f((unsigned short)(v[j] >> 16)), ay[j & 3]);
        }
    }
    for (; i + 8 <= e; i += 8) {
        uint2 ed[8];
#pragma unroll
        for (int j = 0; j < 8; j++) ed[j] = cw[i + j];
        unsigned v[8];
#pragma unroll
        for (int j = 0; j < 8; j++) v[j] = Su[(size_t)ed[j].x * 64 + lane];
#pragma unroll
        for (int j = 0; j < 8; j++) {
            float wj = __uint_as_float(ed[j].y);
            ax[j & 3] = fmaf(wj, bf2f((unsigned short)v[j]), ax[j & 3]);
            ay[j & 3] = fmaf(wj, bf2f((unsigned short)(v[j] >> 16)), ay[j & 3]);
        }
    }
    for (; i + 4 <= e; i += 4) {
        uint2 ed[4];
#pragma unroll
        for (int j = 0; j < 4; j++) ed[j] = cw[i + j];
        unsigned v[4];
#pragma unroll
        for (int j = 0; j < 4; j++) v[j] = Su[(size_t)ed[j].x * 64 + lane];
#pragma unroll
        for (int j = 0; j < 4; j++) {
            float wj = __uint_as_float(ed[j].y);
            ax[j] = fmaf(wj, bf2f((unsigned short)v[j]), ax[j]);
            ay[j] = fmaf(wj, bf2f((unsigned short)(v[j] >> 16)), ay[j]);
        }
    }
    for (; i < e; i++) {
        uint2 ed = cw[i];
        unsigned v = Su[(size_t)ed.x * 64 + lane];
        float wj = __uint_as_float(ed.y);
        ax[0] = fmaf(wj, bf2f((unsigned short)v), ax[0]);
        ay[0] = fmaf(wj, bf2f((unsigned short)(v >> 16)), ay[0]);
    }
    float rx = (ax[0] + ax[1]) + (ax[2] + ax[3]) + bias[lane * 2];
    float ry = (ay[0] + ay[1]) + (ay[2] + ay[3]) + bias[lane * 2 + 1];
    if (do_relu) {
        rx = fmaxf(rx, 0.f);
        ry = fmaxf(ry, 0.f);
    }
    unsigned o = (unsigned)f2bf(rx) | ((unsigned)f2bf(ry) << 16);
    __builtin_nontemporal_store(o, (unsigned*)(out + (size_t)node * NHID) + lane);
}

// ---------------- SpMM (width 40, bf16 pitch 40) + bias + log_softmax -> fp32 out ----------------
// unroll-8 MLP (round-7 version, kept).

__global__ __launch_bounds__(256) void k_spmm40_lsm(const unsigned short* __restrict__ S,
                                                    const int* __restrict__ rp,
                                                    const uint2* __restrict__ cw,
                                                    const float* __restrict__ bias,
                                                    float* __restrict__ out,
                                                    int n) {
    int wid  = threadIdx.x >> 6;
    int lane = threadIdx.x & 63;
    int node = blockIdx.x * 4 + wid;
    if (node >= n) return;
    int s = rp[node], e = rp[node + 1];
    float a0 = 0.f, a1 = 0.f, a2 = 0.f, a3 = 0.f;
    int i = s;
    bool act = lane < NCLASS;
    for (; i + 8 <= e; i += 8) {
        uint2 e0 = cw[i],     e1 = cw[i + 1], e2 = cw[i + 2], e3 = cw[i + 3];
        uint2 e4 = cw[i + 4], e5 = cw[i + 5], e6 = cw[i + 6], e7 = cw[i + 7];
        if (act) {
            float v0 = bf2f(S[(size_t)e0.x * NCLASS + lane]);
            float v1 = bf2f(S[(size_t)e1.x * NCLASS + lane]);
            float v2 = bf2f(S[(size_t)e2.x * NCLASS + lane]);
            float v3 = bf2f(S[(size_t)e3.x * NCLASS + lane]);
            float v4 = bf2f(S[(size_t)e4.x * NCLASS + lane]);
            float v5 = bf2f(S[(size_t)e5.x * NCLASS + lane]);
            float v6 = bf2f(S[(size_t)e6.x * NCLASS + lane]);
            float v7 = bf2f(S[(size_t)e7.x * NCLASS + lane]);
            a0 = fmaf(__uint_as_float(e0.y), v0, a0);
            a1 = fmaf(__uint_as_float(e1.y), v1, a1);
            a2 = fmaf(__uint_as_float(e2.y), v2, a2);
            a3 = fmaf(__uint_as_float(e3.y), v3, a3);
            a0 = fmaf(__uint_as_float(e4.y), v4, a0);
            a1 = fmaf(__uint_as_float(e5.y), v5, a1);
            a2 = fmaf(__uint_as_float(e6.y), v6, a2);
            a3 = fmaf(__uint_as_float(e7.y), v7, a3);
        }
    }
    for (; i + 4 <= e; i += 4) {
        uint2 e0 = cw[i], e1 = cw[i + 1], e2 = cw[i + 2], e3 = cw[i + 3];
        if (act) {
            float v0 = bf2f(S[(size_t)e0.x * NCLASS + lane]);
            float v1 = bf2f(S[(size_t)e1.x * NCLASS + lane]);
            float v2 = bf2f(S[(size_t)e2.x * NCLASS + lane]);
            float v3 = bf2f(S[(size_t)e3.x * NCLASS + lane]);
            a0 = fmaf(__uint_as_float(e0.y), v0, a0);
            a1 = fmaf(__uint_as_float(e1.y), v1, a1);
            a2 = fmaf(__uint_as_float(e2.y), v2, a2);
            a3 = fmaf(__uint_as_float(e3.y), v3, a3);
        }
    }
    for (; i < e; i++) {
        uint2 e0 = cw[i];
        if (act) a0 = fmaf(__uint_as_float(e0.y), bf2f(S[(size_t)e0.x * NCLASS + lane]), a0);
    }
    float acc = (a0 + a1) + (a2 + a3);
    float logit = act ? acc + bias[lane] : -INFINITY;
    float m = logit;
#pragma unroll
    for (int o = 32; o >= 1; o >>= 1) m = fmaxf(m, __shfl_xor(m, o, 64));
    float ex = act ? expf(logit - m) : 0.f;
    float ssum = ex;
#pragma unroll
    for (int o = 32; o >= 1; o >>= 1) ssum += __shfl_xor(ssum, o, 64);
    if (act) {
        float r = logit - m - logf(ssum);
        __builtin_nontemporal_store(r, out + (size_t)node * NCLASS + lane);
    }
}

// ---------------- launch ----------------

extern "C" void kernel_launch(void* const* d_in, const int* in_sizes, int n_in,
                              void* d_out, int out_size, void* d_ws, size_t ws_size,
                              hipStream_t stream) {
    const float* x  = (const float*)d_in[0];
    const int* row  = (const int*)d_in[1];
    const int* col  = (const int*)d_in[2];
    const float* ew = (const float*)d_in[3];
    const float* W1 = (const float*)d_in[4];
    const float* b1 = (const float*)d_in[5];
    const float* W2 = (const float*)d_in[6];
    const float* b2 = (const float*)d_in[7];
    const float* W3 = (const float*)d_in[8];
    const float* b3 = (const float*)d_in[9];
    const float* W4 = (const float*)d_in[10];
    const float* b4 = (const float*)d_in[11];
    float* out = (float*)d_out;

    const int Nn = in_sizes[0] / NFEAT;
    const int E  = in_sizes[1];
    const int NB = (Nn + 255) / 256;
    const int Mpad = (Nn + 127) & ~127;

    char* ws = (char*)d_ws;
    size_t off = 0;
    auto alloc = [&](size_t bytes) {
        size_t o = off;
        off = (off + bytes + 255) & ~(size_t)255;
        return o;
    };
    int*   row_ptr  = (int*)(ws + alloc((size_t)(Nn + 1) * 4));
    int*   counts   = (int*)(ws + alloc((size_t)Nn * 4));       // also reused as cursor
    int*   partials = (int*)(ws + alloc((size_t)NB * 4));
    uint2* csr_cw   = (uint2*)(ws + alloc((size_t)E * 8));
    unsigned short* Sb  = (unsigned short*)(ws + alloc((size_t)Mpad * NHID * 2));
    unsigned short* Hb  = (unsigned short*)(ws + alloc((size_t)Mpad * NHID * 2));
    unsigned short* S4b = (unsigned short*)(ws + alloc((size_t)Mpad * NCLASS * 2));
    unsigned short* Wt1 = (unsigned short*)(ws + alloc((size_t)128 * 512 * 2));
    unsigned short* Wt2 = (unsigned short*)(ws + alloc((size_t)128 * 128 * 2));
    unsigned short* Wt3 = (unsigned short*)(ws + alloc((size_t)128 * 128 * 2));
    unsigned short* Wt4 = (unsigned short*)(ws + alloc((size_t)48 * 128 * 2));

    // ---- fused weight prep + counts zeroing (1 launch) ----
    {
        int total = 65536 + 32768 + 6144;
        if (Nn > total) total = Nn;
        k_prep_all<<<(total + 255) / 256, 256, 0, stream>>>(W1, W2, W3, W4,
                                                            Wt1, Wt2, Wt3, Wt4,
                                                            counts, Nn);
    }

    // ---- CSR build ----
    k_hist<<<(E + 255) / 256, 256, 0, stream>>>(row, E, counts);
    k_block_sum<<<NB, 256, 0, stream>>>(counts, Nn, partials);
    k_scan_partials<<<1, 512, 0, stream>>>(partials, NB);
    k_scan_counts<<<NB, 256, 0, stream>>>(counts, partials, row_ptr, Nn);
    k_scatter<<<(E + 255) / 256, 256, 0, stream>>>(row, col, ew, E, row_ptr, counts, csr_cw);

    const int gblocks = Mpad / 128;
    const int spmm_blocks = (Nn + 3) / 4;

    // layer 1: x @ W1 -> Sb ; spmm+b1+relu -> Hb
    k_gemm_mfma<true, 128, 128, 128><<<gblocks, 256, 0, stream>>>(x, Wt1, Sb, Nn, NFEAT, 512);
    k_spmm128<<<spmm_blocks, 256, 0, stream>>>(Sb, row_ptr, csr_cw, b1, Hb, Nn, 1);
    // layer 2
    k_gemm_mfma<false, 128, 128, 128><<<gblocks, 256, 0, stream>>>(Hb, Wt2, Sb, Nn, NHID, NHID);
    k_spmm128<<<spmm_blocks, 256, 0, stream>>>(Sb, row_ptr, csr_cw, b2, Hb, Nn, 1);
    // layer 3
    k_gemm_mfma<false, 128, 128, 128><<<gblocks, 256, 0, stream>>>(Hb, Wt3, Sb, Nn, NHID, NHID);
    k_spmm128<<<spmm_blocks, 256, 0, stream>>>(Sb, row_ptr, csr_cw, b3, Hb, Nn, 1);
    // layer 4: Hb @ W4 -> S4b[N,40] ; spmm+b4+log_softmax -> out (fp32)
    k_gemm_mfma<false, 48, 40, 40><<<gblocks, 256, 0, stream>>>(Hb, Wt4, S4b, Nn, NHID, NHID);
    k_spmm40_lsm<<<spmm_blocks, 256, 0, stream>>>(S4b, row_ptr, csr_cw, b4, out, Nn);
}